// Round 1
// baseline (14508.064 us; speedup 1.0000x reference)
//
#include <hip/hip_runtime.h>

// Problem constants
#define NB   256      // batch
#define ND   512      // hidden D
#define NH4  2048     // 4*D gates
#define NL   3        // layers
#define NT   201      // timesteps
#define NV   128      // vocab
#define NMID 1024     // mlp mid

typedef _Float16 half8 __attribute__((ext_vector_type(8)));
typedef float f32x4 __attribute__((ext_vector_type(4)));

__device__ __forceinline__ float sigf(float x) { return 1.0f / (1.0f + __expf(-x)); }
__device__ __forceinline__ float tanh_(float x) {
  float e = __expf(-2.0f * fabsf(x));
  float t = (1.0f - e) / (1.0f + e);
  return x < 0.0f ? -t : t;
}

// Monotonic-counter group barrier (32 WGs per group). Counter never resets.
__device__ __forceinline__ void group_barrier(unsigned* cnt) {
  __syncthreads();
  if (threadIdx.x == 0) {
    unsigned old = __hip_atomic_fetch_add(cnt, 1u, __ATOMIC_ACQ_REL, __HIP_MEMORY_SCOPE_AGENT);
    unsigned target = (old & ~31u) + 32u;
    while (__hip_atomic_load(cnt, __ATOMIC_ACQUIRE, __HIP_MEMORY_SCOPE_AGENT) < target)
      __builtin_amdgcn_s_sleep(2);
  }
  __syncthreads();
}

// ---------------- prep kernels ----------------

// Build permuted, combined f16 weights Wp[l][R][k], R = dt*64 + g*16 + di maps to
// gate column col = g*512 + dt*16 + di ; k<512 -> Wih, k>=512 -> Whh. Also bp = bih+bhh.
__global__ void prep_w(const float* __restrict__ Wih, const float* __restrict__ Whh,
                       const float* __restrict__ bih, const float* __restrict__ bhh,
                       _Float16* __restrict__ Wp, float* __restrict__ bp) {
  size_t idx = (size_t)blockIdx.x * 256 + threadIdx.x;   // 3*2048*1024 total
  {
    int k = (int)(idx & 1023);
    int R = (int)((idx >> 10) & 2047);
    int l = (int)(idx >> 21);
    int dt = R >> 6, g = (R >> 4) & 3, di = R & 15;
    int col = g * 512 + dt * 16 + di;
    float v = (k < 512) ? Wih[((size_t)l * NH4 + col) * ND + k]
                        : Whh[((size_t)l * NH4 + col) * ND + (k - 512)];
    Wp[idx] = (_Float16)v;
  }
  if (idx < (size_t)NL * NH4) {
    int R = (int)(idx & 2047);
    int l = (int)(idx >> 11);
    int dt = R >> 6, g = (R >> 4) & 3, di = R & 15;
    int col = g * 512 + dt * 16 + di;
    bp[idx] = bih[l * NH4 + col] + bhh[l * NH4 + col];
  }
}

__global__ void prep_misc(const float* __restrict__ Wvis, const float* __restrict__ feat,
                          const float* __restrict__ embed, const float* __restrict__ W1,
                          const float* __restrict__ W2,
                          _Float16* __restrict__ Wvis16, _Float16* __restrict__ feat16,
                          _Float16* __restrict__ x0, _Float16* __restrict__ W1h,
                          _Float16* __restrict__ W2h, unsigned* __restrict__ cnt) {
  int idx = blockIdx.x * 256 + threadIdx.x;   // grid covers 524288
  if (idx < 512 * 512)  Wvis16[idx] = (_Float16)Wvis[idx];
  if (idx < 256 * 512)  feat16[idx] = (_Float16)feat[idx];
  if (idx < 256 * 512)  x0[idx]     = (_Float16)embed[idx & 511];   // embed[START_IDX=0]
  if (idx < 1024 * 512) W1h[idx]    = (_Float16)W1[idx];
  if (idx < 128 * 1024) W2h[idx]    = (_Float16)W2[idx];
  if (idx < 1024) cnt[idx] = 0;
}

// ---------------- persistent LSTM kernel ----------------
// 256 WGs x 256 threads. WG(bid): mg = bid&7 (batch rows m0=mg*32), dt = bid>>3 (hidden dims d0=dt*16).
// Group = 32 WGs sharing mg; one barrier per (t,l) unit. c-state in registers.
__global__ __launch_bounds__(256, 1) void lstm_persist(
    const _Float16* __restrict__ Wp,     // [3][2048][1024]
    const float* __restrict__ bp,        // [3][2048]
    const _Float16* __restrict__ Wvis,   // [512][512]
    const float* __restrict__ bvis,      // [512]
    const _Float16* __restrict__ feat16, // [256][512]
    const _Float16* __restrict__ x0,     // [256][512]
    _Float16* __restrict__ featp,        // [256][512]
    _Float16* __restrict__ hbuf,         // [3][2][256][512]
    _Float16* __restrict__ res,          // [201][256][512]  (rows r = t*256+b)
    unsigned* __restrict__ cntbase) {
  const int bid = blockIdx.x;
  const int mg = bid & 7, dt = bid >> 3;
  const int m0 = mg * 32, d0 = dt * 16;
  const int tid = threadIdx.x;
  const int lane = tid & 63, w = tid >> 6;
  const int lr = lane & 15, lg = lane >> 4;
  const int wm = w & 1, wn = w >> 1;

  __shared__ float glds[4][32][16];
  unsigned* mycnt = cntbase + mg * 64;   // 256B-spaced counters

  // ---- prologue: feat_p = feat@Wvis^T+bvis ; h0 = feat_p@Wvis^T+bvis ----
  {
    const int wm2 = w & 1, wk = w >> 1;
    #pragma unroll
    for (int pg = 0; pg < 2; ++pg) {
      const _Float16* A = pg ? featp : feat16;
      f32x4 pacc = {0.f, 0.f, 0.f, 0.f};
      #pragma unroll
      for (int kc = 0; kc < 8; ++kc) {
        int kcc = wk * 8 + kc;
        half8 a  = *(const half8*)(A    + (size_t)(m0 + wm2 * 16 + lr) * ND + kcc * 32 + lg * 8);
        half8 bb = *(const half8*)(Wvis + (size_t)(d0 + lr) * ND + kcc * 32 + lg * 8);
        pacc = __builtin_amdgcn_mfma_f32_16x16x32_f16(a, bb, pacc, 0, 0, 0);
      }
      #pragma unroll
      for (int j = 0; j < 4; ++j) glds[wk][wm2 * 16 + lg * 4 + j][lr] = pacc[j];
      __syncthreads();
      #pragma unroll
      for (int ci = 0; ci < 2; ++ci) {
        int cell = tid + ci * 256;
        int m = cell >> 4, d = cell & 15;
        float v = glds[0][m][d] + glds[1][m][d] + bvis[d0 + d];
        _Float16 hv = (_Float16)v;
        size_t off = (size_t)(m0 + m) * ND + d0 + d;
        if (pg == 0) {
          featp[off] = hv;
        } else {
          hbuf[(size_t)(0 * 2 + 1) * (NB * ND) + off] = hv;
          hbuf[(size_t)(1 * 2 + 1) * (NB * ND) + off] = hv;
          hbuf[(size_t)(2 * 2 + 1) * (NB * ND) + off] = hv;
        }
      }
      group_barrier(mycnt);
    }
  }

  // ---- main recurrence ----
  float creg[3][2] = {{0.f, 0.f}, {0.f, 0.f}, {0.f, 0.f}};
  const size_t arow = (size_t)(m0 + wm * 16 + lr) * ND;

  #pragma unroll 1
  for (int t = 0; t < NT; ++t) {
    #pragma unroll
    for (int l = 0; l < 3; ++l) {
      const _Float16* xsrc;
      if (l == 0)
        xsrc = (t == 0) ? x0 : (hbuf + (size_t)(2 * 2 + ((t + 1) & 1)) * (NB * ND));
      else
        xsrc = hbuf + (size_t)((l - 1) * 2 + (t & 1)) * (NB * ND);
      const _Float16* hsrc = hbuf + (size_t)(l * 2 + ((t + 1) & 1)) * (NB * ND);
      _Float16* hdst       = hbuf + (size_t)(l * 2 + (t & 1)) * (NB * ND);

      f32x4 acc0 = {0.f, 0.f, 0.f, 0.f}, acc1 = {0.f, 0.f, 0.f, 0.f};
      const _Float16* wbase = Wp + ((size_t)l * NH4 + dt * 64 + wn * 32 + lr) * 1024;
      #pragma unroll 8
      for (int kc = 0; kc < 32; ++kc) {
        const _Float16* asrc = (kc < 16) ? xsrc : hsrc;
        half8 a  = *(const half8*)(asrc + arow + (kc & 15) * 32 + lg * 8);
        half8 b0 = *(const half8*)(wbase + kc * 32 + lg * 8);
        half8 b1 = *(const half8*)(wbase + 16 * 1024 + kc * 32 + lg * 8);
        acc0 = __builtin_amdgcn_mfma_f32_16x16x32_f16(a, b0, acc0, 0, 0, 0);
        acc1 = __builtin_amdgcn_mfma_f32_16x16x32_f16(a, b1, acc1, 0, 0, 0);
      }
      #pragma unroll
      for (int j = 0; j < 4; ++j) {
        glds[wn * 2 + 0][wm * 16 + lg * 4 + j][lr] = acc0[j];
        glds[wn * 2 + 1][wm * 16 + lg * 4 + j][lr] = acc1[j];
      }
      __syncthreads();
      const float* bpl = bp + l * NH4 + dt * 64;
      #pragma unroll
      for (int ci = 0; ci < 2; ++ci) {
        int cell = tid + ci * 256;
        int m = cell >> 4, d = cell & 15;
        float gi = glds[0][m][d] + bpl[0 + d];
        float gf = glds[1][m][d] + bpl[16 + d];
        float gg = glds[2][m][d] + bpl[32 + d];
        float go = glds[3][m][d] + bpl[48 + d];
        float c = creg[l][ci];
        c = sigf(gf) * c + sigf(gi) * tanh_(gg);
        float h = sigf(go) * tanh_(c);
        creg[l][ci] = c;
        _Float16 hv = (_Float16)h;
        size_t off = (size_t)(m0 + m) * ND + d0 + d;
        hdst[off] = hv;
        if (l == 2) res[(size_t)t * (NB * ND) + off] = hv;
      }
      group_barrier(mycnt);
    }
  }
}

// ---------------- fused MLP head ----------------
// Per 64-row tile: mid = gelu(res@W1^T+b1) chunked (8 x 128 cols) through LDS,
// logits = mid@W2^T+b2, scatter-store out[b][v][t].
__global__ __launch_bounds__(256, 2) void head_kernel(
    const _Float16* __restrict__ res,  // [51456][512]
    const _Float16* __restrict__ W1h,  // [1024][512]
    const float* __restrict__ b1,      // [1024]
    const _Float16* __restrict__ W2h,  // [128][1024]
    const float* __restrict__ b2,      // [128]
    float* __restrict__ out) {         // [256][128][201]
  const int tile = blockIdx.x;         // 0..803
  const int tid = threadIdx.x;
  const int lane = tid & 63, w = tid >> 6;
  const int lr = lane & 15, lg = lane >> 4;
  const int r0 = tile * 64;

  __shared__ _Float16 mid[64][128];    // XOR-swizzled 16B blocks

  f32x4 acc2[8];
  #pragma unroll
  for (int n = 0; n < 8; ++n) acc2[n] = (f32x4){0.f, 0.f, 0.f, 0.f};

  const size_t arow = (size_t)(r0 + w * 16 + lr) * ND;

  #pragma unroll 1
  for (int nc = 0; nc < 8; ++nc) {
    f32x4 acc1[8];
    #pragma unroll
    for (int n = 0; n < 8; ++n) acc1[n] = (f32x4){0.f, 0.f, 0.f, 0.f};
    #pragma unroll 2
    for (int kc = 0; kc < 16; ++kc) {
      half8 a = *(const half8*)(res + arow + kc * 32 + lg * 8);
      #pragma unroll
      for (int n = 0; n < 8; ++n) {
        half8 bb = *(const half8*)(W1h + (size_t)(nc * 128 + n * 16 + lr) * ND + kc * 32 + lg * 8);
        acc1[n] = __builtin_amdgcn_mfma_f32_16x16x32_f16(a, bb, acc1[n], 0, 0, 0);
      }
    }
    __syncthreads();   // previous chunk's mid reads done
    #pragma unroll
    for (int n = 0; n < 8; ++n) {
      #pragma unroll
      for (int j = 0; j < 4; ++j) {
        int m = w * 16 + lg * 4 + j;
        int col = n * 16 + lr;
        float v = acc1[n][j] + b1[nc * 128 + col];
        v = 0.5f * v * (1.0f + erff(v * 0.7071067811865475f));   // exact gelu
        int sw = (((col >> 3) ^ (m & 15)) << 3) + (col & 7);
        mid[m][sw] = (_Float16)v;
      }
    }
    __syncthreads();
    #pragma unroll
    for (int kc2 = 0; kc2 < 4; ++kc2) {
      int row = w * 16 + lr;
      int blk = (kc2 * 4 + lg) ^ (row & 15);
      half8 a2 = *(const half8*)(&mid[row][blk * 8]);
      #pragma unroll
      for (int n = 0; n < 8; ++n) {
        half8 bb = *(const half8*)(W2h + (size_t)(n * 16 + lr) * NMID + nc * 128 + kc2 * 32 + lg * 8);
        acc2[n] = __builtin_amdgcn_mfma_f32_16x16x32_f16(a2, bb, acc2[n], 0, 0, 0);
      }
    }
  }
  #pragma unroll
  for (int n = 0; n < 8; ++n) {
    #pragma unroll
    for (int j = 0; j < 4; ++j) {
      int r = r0 + w * 16 + lg * 4 + j;
      int b = r & 255, t = r >> 8;     // rows are r = t*256 + b
      int v = n * 16 + lr;
      out[((size_t)b * NV + v) * NT + t] = acc2[n][j] + b2[v];
    }
  }
}

// ---------------- launch ----------------
extern "C" void kernel_launch(void* const* d_in, const int* in_sizes, int n_in,
                              void* d_out, int out_size, void* d_ws, size_t ws_size,
                              hipStream_t stream) {
  const float* feat  = (const float*)d_in[0];
  const float* Wvis  = (const float*)d_in[1];
  const float* bvis  = (const float*)d_in[2];
  const float* embed = (const float*)d_in[3];
  const float* Wih   = (const float*)d_in[4];
  const float* Whh   = (const float*)d_in[5];
  const float* bih   = (const float*)d_in[6];
  const float* bhh   = (const float*)d_in[7];
  const float* W1    = (const float*)d_in[8];
  const float* b1    = (const float*)d_in[9];
  const float* W2    = (const float*)d_in[10];
  const float* b2    = (const float*)d_in[11];
  float* out = (float*)d_out;

  char* p = (char*)d_ws;
  _Float16* Wp     = (_Float16*)p; p += (size_t)NL * NH4 * 1024 * 2;   // 12.58 MB
  _Float16* Wvis16 = (_Float16*)p; p += (size_t)512 * 512 * 2;
  _Float16* feat16 = (_Float16*)p; p += (size_t)256 * 512 * 2;
  _Float16* x0     = (_Float16*)p; p += (size_t)256 * 512 * 2;
  _Float16* featp  = (_Float16*)p; p += (size_t)256 * 512 * 2;
  _Float16* hbuf   = (_Float16*)p; p += (size_t)NL * 2 * NB * ND * 2;
  _Float16* resb   = (_Float16*)p; p += (size_t)NT * NB * ND * 2;      // 52.7 MB
  _Float16* W1h    = (_Float16*)p; p += (size_t)NMID * ND * 2;
  _Float16* W2h    = (_Float16*)p; p += (size_t)NV * NMID * 2;
  float*    bp     = (float*)p;    p += (size_t)NL * NH4 * 4;
  unsigned* cnt    = (unsigned*)p; p += 4096;

  prep_w<<<24576, 256, 0, stream>>>(Wih, Whh, bih, bhh, Wp, bp);
  prep_misc<<<2048, 256, 0, stream>>>(Wvis, feat, embed, W1, W2,
                                      Wvis16, feat16, x0, W1h, W2h, cnt);
  lstm_persist<<<256, 256, 0, stream>>>(Wp, bp, Wvis16, bvis, feat16, x0,
                                        featp, hbuf, resb, cnt);
  head_kernel<<<804, 256, 0, stream>>>(resb, W1h, b1, W2h, b2, out);
  (void)in_sizes; (void)n_in; (void)out_size; (void)ws_size;
}